// Round 4
// baseline (1192.938 us; speedup 1.0000x reference)
//
#include <hip/hip_runtime.h>
#include <hip/hip_bf16.h>

#define FDIM 64
#define BNODES 64          // nodes per bucket (dst >> 6)
#define CHUNK 4096         // edges per partition chunk
#define HPAD 68            // padded LDS row

// ---- pass 1: per-chunk bucket histogram (LDS) ----
__global__ __launch_bounds__(256) void bucket_hist(const int* __restrict__ dst,
                                                   int* __restrict__ hist,
                                                   int n_edges, int nbuck) {
    __shared__ int lh[1024];               // nbuck <= 1024
    int chunk = blockIdx.x;
    for (int i = threadIdx.x; i < nbuck; i += 256) lh[i] = 0;
    __syncthreads();
    int beg = chunk * CHUNK;
    int end = min(beg + CHUNK, n_edges);
    for (int e = beg + threadIdx.x; e < end; e += 256)
        atomicAdd(&lh[dst[e] >> 6], 1);
    __syncthreads();
    for (int i = threadIdx.x; i < nbuck; i += 256)
        hist[(size_t)chunk * nbuck + i] = lh[i];
}

// ---- pass 2a: per-bucket exclusive scan over chunks ----
__global__ __launch_bounds__(256) void scan_chunks(const int* __restrict__ hist,
                                                   int* __restrict__ chunk_off,
                                                   int* __restrict__ bucket_total,
                                                   int nchunks, int nbuck) {
    __shared__ int s[256];                 // nchunks <= 256
    int b = blockIdx.x;
    int t = threadIdx.x;
    int v = (t < nchunks) ? hist[(size_t)t * nbuck + b] : 0;
    s[t] = v;
    __syncthreads();
    for (int off = 1; off < 256; off <<= 1) {
        int u = (t >= off) ? s[t - off] : 0;
        __syncthreads();
        s[t] += u;
        __syncthreads();
    }
    if (t < nchunks) chunk_off[(size_t)t * nbuck + b] = s[t] - v;  // exclusive
    if (t == 255) bucket_total[b] = s[255];
}

// ---- pass 2b: exclusive scan of bucket totals ----
__global__ __launch_bounds__(1024) void scan_buckets(const int* __restrict__ bucket_total,
                                                     int* __restrict__ bucket_start,
                                                     int nbuck, int n_edges) {
    __shared__ int s[1024];                // nbuck <= 1024
    int t = threadIdx.x;
    int v = (t < nbuck) ? bucket_total[t] : 0;
    s[t] = v;
    __syncthreads();
    for (int off = 1; off < 1024; off <<= 1) {
        int u = (t >= off) ? s[t - off] : 0;
        __syncthreads();
        s[t] += u;
        __syncthreads();
    }
    if (t < nbuck) bucket_start[t] = s[t] - v;
    if (t == 0) bucket_start[nbuck] = n_edges;
}

// ---- pass 3: fill packed edges, (chunk,bucket)-contiguous runs ----
__global__ __launch_bounds__(256) void bucket_fill(const int* __restrict__ src,
                                                   const int* __restrict__ dst,
                                                   const int* __restrict__ bucket_start,
                                                   const int* __restrict__ chunk_off,
                                                   unsigned int* __restrict__ packed,
                                                   int n_edges, int nbuck) {
    __shared__ int cur[1024];
    int chunk = blockIdx.x;
    for (int i = threadIdx.x; i < nbuck; i += 256)
        cur[i] = bucket_start[i] + chunk_off[(size_t)chunk * nbuck + i];
    __syncthreads();
    int beg = chunk * CHUNK;
    int end = min(beg + CHUNK, n_edges);
    for (int e = beg + threadIdx.x; e < end; e += 256) {
        int d = dst[e];
        int b = d >> 6;
        int pos = atomicAdd(&cur[b], 1);
        packed[pos] = (unsigned int)src[e] | ((unsigned int)(d & 63) << 16);
    }
}

// ---- fused GIN conv: aggregate (LDS atomics) + 2-layer MLP (+ optional final linear) ----
__global__ __launch_bounds__(1024, 8) void gin_conv(const float* __restrict__ x,
        const unsigned int* __restrict__ packed,
        const int* __restrict__ bucket_start,
        const float* __restrict__ W1, const float* __restrict__ b1,
        const float* __restrict__ W2, const float* __restrict__ b2,
        const float* __restrict__ Wl, const float* __restrict__ bl,
        float* __restrict__ y, float* __restrict__ out,
        int n_nodes, int do_final) {
    __shared__ float sh[BNODES * HPAD];
    __shared__ float sg[BNODES * HPAD];
    __shared__ float sW1[FDIM * FDIM];
    __shared__ float sW2[FDIM * FDIM];
    __shared__ float sb1[FDIM], sb2[FDIM];
    __shared__ float sWl[FDIM * 10];
    __shared__ float sbl[16];

    int tid = threadIdx.x;
    int b = blockIdx.x;
    int base = b * BNODES;

    // stage weights: 4096 floats each, exactly one float4 per thread
    ((float4*)sW1)[tid] = ((const float4*)W1)[tid];
    ((float4*)sW2)[tid] = ((const float4*)W2)[tid];
    if (tid < FDIM) { sb1[tid] = b1[tid]; sb2[tid] = b2[tid]; }
    if (do_final) {
        for (int i = tid; i < FDIM * 10; i += 1024) sWl[i] = Wl[i];
        if (tid < 10) sbl[tid] = bl[tid];
    }
    // stage self rows (h starts as x[node])
    {
        int r = tid >> 4, c = (tid & 15) * 4;
        int node = base + r;
        float4 v = make_float4(0.f, 0.f, 0.f, 0.f);
        if (node < n_nodes) v = *(const float4*)(x + (size_t)node * FDIM + c);
        *(float4*)(&sh[r * HPAD + c]) = v;
    }
    __syncthreads();

    // edge aggregation: 16 threads/edge, coalesced 256B row reads, LDS atomics
    {
        int ebeg = bucket_start[b], eend = bucket_start[b + 1];
        int group = tid >> 4;
        int c = (tid & 15) * 4;
        int e = ebeg + group;
        for (; e + 64 < eend; e += 128) {
            unsigned int p0 = packed[e];
            unsigned int p1 = packed[e + 64];
            int s0 = p0 & 0xFFFF, d0 = p0 >> 16;
            int s1 = p1 & 0xFFFF, d1 = p1 >> 16;
            float4 v0 = *(const float4*)(x + (size_t)s0 * FDIM + c);
            float4 v1 = *(const float4*)(x + (size_t)s1 * FDIM + c);
            float* h0 = &sh[d0 * HPAD + c];
            float* h1 = &sh[d1 * HPAD + c];
            atomicAdd(h0 + 0, v0.x); atomicAdd(h0 + 1, v0.y);
            atomicAdd(h0 + 2, v0.z); atomicAdd(h0 + 3, v0.w);
            atomicAdd(h1 + 0, v1.x); atomicAdd(h1 + 1, v1.y);
            atomicAdd(h1 + 2, v1.z); atomicAdd(h1 + 3, v1.w);
        }
        if (e < eend) {
            unsigned int p0 = packed[e];
            int s0 = p0 & 0xFFFF, d0 = p0 >> 16;
            float4 v0 = *(const float4*)(x + (size_t)s0 * FDIM + c);
            float* h0 = &sh[d0 * HPAD + c];
            atomicAdd(h0 + 0, v0.x); atomicAdd(h0 + 1, v0.y);
            atomicAdd(h0 + 2, v0.z); atomicAdd(h0 + 3, v0.w);
        }
    }
    __syncthreads();

    // MLP: 16 threads per node; thread computes 4 output features
    int nl = tid >> 4;              // 0..63
    int jq = (tid & 15) * 4;

    // layer 1: g = relu(h @ W1 + b1)
    float a0 = sb1[jq], a1 = sb1[jq + 1], a2 = sb1[jq + 2], a3 = sb1[jq + 3];
#pragma unroll
    for (int k0 = 0; k0 < FDIM; k0 += 4) {
        float4 hv = *(float4*)(&sh[nl * HPAD + k0]);
        float4 w0 = *(float4*)(&sW1[(k0 + 0) * FDIM + jq]);
        float4 w1 = *(float4*)(&sW1[(k0 + 1) * FDIM + jq]);
        float4 w2 = *(float4*)(&sW1[(k0 + 2) * FDIM + jq]);
        float4 w3 = *(float4*)(&sW1[(k0 + 3) * FDIM + jq]);
        a0 += hv.x * w0.x + hv.y * w1.x + hv.z * w2.x + hv.w * w3.x;
        a1 += hv.x * w0.y + hv.y * w1.y + hv.z * w2.y + hv.w * w3.y;
        a2 += hv.x * w0.z + hv.y * w1.z + hv.z * w2.z + hv.w * w3.z;
        a3 += hv.x * w0.w + hv.y * w1.w + hv.z * w2.w + hv.w * w3.w;
    }
    float4 gq;
    gq.x = fmaxf(a0, 0.f); gq.y = fmaxf(a1, 0.f);
    gq.z = fmaxf(a2, 0.f); gq.w = fmaxf(a3, 0.f);
    *(float4*)(&sg[nl * HPAD + jq]) = gq;
    __syncthreads();

    // layer 2: o = relu(g @ W2 + b2)
    float c0 = sb2[jq], c1 = sb2[jq + 1], c2 = sb2[jq + 2], c3 = sb2[jq + 3];
#pragma unroll
    for (int k0 = 0; k0 < FDIM; k0 += 4) {
        float4 gv = *(float4*)(&sg[nl * HPAD + k0]);
        float4 w0 = *(float4*)(&sW2[(k0 + 0) * FDIM + jq]);
        float4 w1 = *(float4*)(&sW2[(k0 + 1) * FDIM + jq]);
        float4 w2 = *(float4*)(&sW2[(k0 + 2) * FDIM + jq]);
        float4 w3 = *(float4*)(&sW2[(k0 + 3) * FDIM + jq]);
        c0 += gv.x * w0.x + gv.y * w1.x + gv.z * w2.x + gv.w * w3.x;
        c1 += gv.x * w0.y + gv.y * w1.y + gv.z * w2.y + gv.w * w3.y;
        c2 += gv.x * w0.z + gv.y * w1.z + gv.z * w2.z + gv.w * w3.z;
        c3 += gv.x * w0.w + gv.y * w1.w + gv.z * w2.w + gv.w * w3.w;
    }
    float4 o;
    o.x = fmaxf(c0, 0.f); o.y = fmaxf(c1, 0.f);
    o.z = fmaxf(c2, 0.f); o.w = fmaxf(c3, 0.f);

    if (!do_final) {
        int node = base + nl;
        if (node < n_nodes)
            *(float4*)(y + (size_t)node * FDIM + jq) = o;
    } else {
        // park o in sh (free after layer 1), then fused final linear
        *(float4*)(&sh[nl * HPAD + jq]) = o;
        __syncthreads();
        if (tid < BNODES * 10) {
            int n = tid / 10, cc = tid % 10;
            int node = base + n;
            if (node < n_nodes) {
                float acc = sbl[cc];
#pragma unroll
                for (int k = 0; k < FDIM; k++)
                    acc += sh[n * HPAD + k] * sWl[k * 10 + cc];
                out[(size_t)node * 10 + cc] = acc;
            }
        }
    }
}

extern "C" void kernel_launch(void* const* d_in, const int* in_sizes, int n_in,
                              void* d_out, int out_size, void* d_ws, size_t ws_size,
                              hipStream_t stream) {
    const float* features = (const float*)d_in[0];
    const int* edges = (const int*)d_in[1];
    int n_nodes = in_sizes[0] / FDIM;          // 50000
    int n_edges = in_sizes[1] / 2;             // 800000
    const int* src = edges;
    const int* dst = edges + n_edges;

    int nbuck = (n_nodes + BNODES - 1) / BNODES;     // 782  (<=1024)
    int nchunks = (n_edges + CHUNK - 1) / CHUNK;     // 196  (<=256)

    // workspace: hist | chunk_off | bucket_total | bucket_start | packed | xA | xB
    int* hist = (int*)d_ws;
    int* chunk_off = hist + (size_t)nchunks * nbuck;
    int* bucket_total = chunk_off + (size_t)nchunks * nbuck;
    int* bucket_start = bucket_total + nbuck;
    unsigned int* packed = (unsigned int*)(bucket_start + nbuck + 1);
    size_t int_elems = 2 * (size_t)nchunks * nbuck + 2 * (size_t)nbuck + 1 + n_edges;
    int_elems = (int_elems + 3) & ~(size_t)3;
    float* xA = (float*)d_ws + int_elems;
    float* xB = xA + (size_t)n_nodes * FDIM;

    // --- build bucketed edge list ---
    bucket_hist<<<nchunks, 256, 0, stream>>>(dst, hist, n_edges, nbuck);
    scan_chunks<<<nbuck, 256, 0, stream>>>(hist, chunk_off, bucket_total, nchunks, nbuck);
    scan_buckets<<<1, 1024, 0, stream>>>(bucket_total, bucket_start, nbuck, n_edges);
    bucket_fill<<<nchunks, 256, 0, stream>>>(src, dst, bucket_start, chunk_off, packed, n_edges, nbuck);

    // --- 3 fused GIN convs (last one also does the final linear) ---
    const float* Wl = (const float*)d_in[14];
    const float* bl = (const float*)d_in[15];
    const float* xc = features;
    float* ybuf[2] = {xA, xB};
    for (int conv = 0; conv < 3; conv++) {
        const float* W1 = (const float*)d_in[2 + 4 * conv];
        const float* b1 = (const float*)d_in[3 + 4 * conv];
        const float* W2 = (const float*)d_in[4 + 4 * conv];
        const float* b2 = (const float*)d_in[5 + 4 * conv];
        int fin = (conv == 2) ? 1 : 0;
        gin_conv<<<nbuck, 1024, 0, stream>>>(xc, packed, bucket_start,
                                             W1, b1, W2, b2, Wl, bl,
                                             ybuf[conv & 1], (float*)d_out,
                                             n_nodes, fin);
        xc = ybuf[conv & 1];
    }
}

// Round 5
// 316.845 us; speedup vs baseline: 3.7651x; 3.7651x over previous
//
#include <hip/hip_runtime.h>
#include <hip/hip_bf16.h>

#define FDIM 64
#define BNODES 64          // nodes per bucket (dst >> 6)
#define CHUNK 8192         // edges per partition chunk
#define HPAD 68            // padded LDS row

// ---- pass 1: per-chunk bucket histogram (LDS) ----
__global__ __launch_bounds__(256) void bucket_hist(const int* __restrict__ dst,
                                                   int* __restrict__ hist,
                                                   int n_edges, int nbuck) {
    __shared__ int lh[1024];               // nbuck <= 1024
    int chunk = blockIdx.x;
    for (int i = threadIdx.x; i < nbuck; i += 256) lh[i] = 0;
    __syncthreads();
    int beg = chunk * CHUNK;
    int end = min(beg + CHUNK, n_edges);
    for (int e = beg + threadIdx.x; e < end; e += 256)
        atomicAdd(&lh[dst[e] >> 6], 1);
    __syncthreads();
    for (int i = threadIdx.x; i < nbuck; i += 256)
        hist[(size_t)chunk * nbuck + i] = lh[i];
}

// ---- pass 2a: per-bucket exclusive scan over chunks ----
__global__ __launch_bounds__(256) void scan_chunks(const int* __restrict__ hist,
                                                   int* __restrict__ chunk_off,
                                                   int* __restrict__ bucket_total,
                                                   int nchunks, int nbuck) {
    __shared__ int s[256];                 // nchunks <= 256
    int b = blockIdx.x;
    int t = threadIdx.x;
    int v = (t < nchunks) ? hist[(size_t)t * nbuck + b] : 0;
    s[t] = v;
    __syncthreads();
    for (int off = 1; off < 256; off <<= 1) {
        int u = (t >= off) ? s[t - off] : 0;
        __syncthreads();
        s[t] += u;
        __syncthreads();
    }
    if (t < nchunks) chunk_off[(size_t)t * nbuck + b] = s[t] - v;  // exclusive
    if (t == 255) bucket_total[b] = s[255];
}

// ---- pass 2b: exclusive scan of bucket totals ----
__global__ __launch_bounds__(1024) void scan_buckets(const int* __restrict__ bucket_total,
                                                     int* __restrict__ bucket_start,
                                                     int* __restrict__ row_ptr,
                                                     int nbuck, int n_nodes, int n_edges) {
    __shared__ int s[1024];                // nbuck <= 1024
    int t = threadIdx.x;
    int v = (t < nbuck) ? bucket_total[t] : 0;
    s[t] = v;
    __syncthreads();
    for (int off = 1; off < 1024; off <<= 1) {
        int u = (t >= off) ? s[t - off] : 0;
        __syncthreads();
        s[t] += u;
        __syncthreads();
    }
    if (t < nbuck) bucket_start[t] = s[t] - v;
    if (t == 0) { bucket_start[nbuck] = n_edges; row_ptr[n_nodes] = n_edges; }
}

// ---- pass 3: fill packed edges, (chunk,bucket)-contiguous runs ----
__global__ __launch_bounds__(256) void bucket_fill(const int* __restrict__ src,
                                                   const int* __restrict__ dst,
                                                   const int* __restrict__ bucket_start,
                                                   const int* __restrict__ chunk_off,
                                                   unsigned int* __restrict__ packed,
                                                   int n_edges, int nbuck) {
    __shared__ int cur[1024];
    int chunk = blockIdx.x;
    for (int i = threadIdx.x; i < nbuck; i += 256)
        cur[i] = bucket_start[i] + chunk_off[(size_t)chunk * nbuck + i];
    __syncthreads();
    int beg = chunk * CHUNK;
    int end = min(beg + CHUNK, n_edges);
    for (int e = beg + threadIdx.x; e < end; e += 256) {
        int d = dst[e];
        int b = d >> 6;
        int pos = atomicAdd(&cur[b], 1);
        packed[pos] = (unsigned int)src[e] | ((unsigned int)(d & 63) << 16);
    }
}

// ---- pass 4: within-bucket sort to node granularity + row_ptr emit ----
__global__ __launch_bounds__(256) void sort_bucket(const unsigned int* __restrict__ packed,
                                                   const int* __restrict__ bucket_start,
                                                   int* __restrict__ src_sorted,
                                                   int* __restrict__ row_ptr, int n_nodes) {
    __shared__ int cnt[BNODES];
    __shared__ int cur[BNODES];
    int b = blockIdx.x;
    int beg = bucket_start[b], end = bucket_start[b + 1];
    if (threadIdx.x < BNODES) cnt[threadIdx.x] = 0;
    __syncthreads();
    for (int e = beg + threadIdx.x; e < end; e += 256)
        atomicAdd(&cnt[packed[e] >> 16], 1);
    __syncthreads();
    if (threadIdx.x == 0) {
        int run = beg;
        for (int i = 0; i < BNODES; i++) { cur[i] = run; run += cnt[i]; }
    }
    __syncthreads();
    if (threadIdx.x < BNODES) {
        int node = b * BNODES + threadIdx.x;
        if (node < n_nodes) row_ptr[node] = cur[threadIdx.x];
    }
    __syncthreads();
    for (int e = beg + threadIdx.x; e < end; e += 256) {
        unsigned int p = packed[e];
        int pos = atomicAdd(&cur[p >> 16], 1);
        src_sorted[pos] = (int)(p & 0xFFFFu);
    }
}

// gather: h[n] = x[n] + sum_{e in row} x[src_sorted[e]] ; 16 threads/node, 4x unroll
__global__ __launch_bounds__(256) void gather_nodes(const float* __restrict__ x,
                                                    const int* __restrict__ row_ptr,
                                                    const int* __restrict__ src_sorted,
                                                    float* __restrict__ h, int n_nodes) {
    int t = blockIdx.x * blockDim.x + threadIdx.x;
    int node = t >> 4;
    if (node >= n_nodes) return;
    int c = (t & 15) * 4;
    int beg = row_ptr[node];
    int end = row_ptr[node + 1];
    float4 acc = *(const float4*)(x + (size_t)node * FDIM + c);
    int e = beg;
    for (; e + 3 < end; e += 4) {
        int s0 = src_sorted[e];
        int s1 = src_sorted[e + 1];
        int s2 = src_sorted[e + 2];
        int s3 = src_sorted[e + 3];
        float4 v0 = *(const float4*)(x + (size_t)s0 * FDIM + c);
        float4 v1 = *(const float4*)(x + (size_t)s1 * FDIM + c);
        float4 v2 = *(const float4*)(x + (size_t)s2 * FDIM + c);
        float4 v3 = *(const float4*)(x + (size_t)s3 * FDIM + c);
        acc.x += (v0.x + v1.x) + (v2.x + v3.x);
        acc.y += (v0.y + v1.y) + (v2.y + v3.y);
        acc.z += (v0.z + v1.z) + (v2.z + v3.z);
        acc.w += (v0.w + v1.w) + (v2.w + v3.w);
    }
    for (; e < end; e++) {
        int s0 = src_sorted[e];
        float4 v0 = *(const float4*)(x + (size_t)s0 * FDIM + c);
        acc.x += v0.x; acc.y += v0.y; acc.z += v0.z; acc.w += v0.w;
    }
    *(float4*)(h + (size_t)node * FDIM + c) = acc;
}

// MLP, 16 threads per node; h/g tiles + W1/W2 staged in LDS
__global__ __launch_bounds__(256) void mlp_relu2(const float* __restrict__ x,
                                                 const float* __restrict__ W1,
                                                 const float* __restrict__ b1,
                                                 const float* __restrict__ W2,
                                                 const float* __restrict__ b2,
                                                 float* __restrict__ y, int n_nodes) {
    __shared__ float sW1[FDIM * FDIM];
    __shared__ float sW2[FDIM * FDIM];
    __shared__ float sb1[FDIM];
    __shared__ float sb2[FDIM];
    __shared__ float sh[16 * HPAD];
    __shared__ float sg[16 * HPAD];
    int tid = threadIdx.x;
    for (int i = tid; i < FDIM * FDIM; i += 256) {
        sW1[i] = W1[i];
        sW2[i] = W2[i];
    }
    if (tid < FDIM) { sb1[tid] = b1[tid]; sb2[tid] = b2[tid]; }

    int base = blockIdx.x * 16;
    {
        int n = tid >> 4;
        int c4 = (tid & 15) * 4;
        float4 v = *(const float4*)(x + (size_t)(base + n) * FDIM + c4);
        *(float4*)(&sh[n * HPAD + c4]) = v;
    }
    __syncthreads();

    int nl = tid >> 4;
    int jq = (tid & 15) * 4;

    float a0 = sb1[jq], a1 = sb1[jq + 1], a2 = sb1[jq + 2], a3 = sb1[jq + 3];
#pragma unroll
    for (int k0 = 0; k0 < FDIM; k0 += 4) {
        float4 hv = *(float4*)(&sh[nl * HPAD + k0]);
        float4 w0 = *(float4*)(&sW1[(k0 + 0) * FDIM + jq]);
        float4 w1 = *(float4*)(&sW1[(k0 + 1) * FDIM + jq]);
        float4 w2 = *(float4*)(&sW1[(k0 + 2) * FDIM + jq]);
        float4 w3 = *(float4*)(&sW1[(k0 + 3) * FDIM + jq]);
        a0 += hv.x * w0.x + hv.y * w1.x + hv.z * w2.x + hv.w * w3.x;
        a1 += hv.x * w0.y + hv.y * w1.y + hv.z * w2.y + hv.w * w3.y;
        a2 += hv.x * w0.z + hv.y * w1.z + hv.z * w2.z + hv.w * w3.z;
        a3 += hv.x * w0.w + hv.y * w1.w + hv.z * w2.w + hv.w * w3.w;
    }
    float4 gq;
    gq.x = fmaxf(a0, 0.f); gq.y = fmaxf(a1, 0.f);
    gq.z = fmaxf(a2, 0.f); gq.w = fmaxf(a3, 0.f);
    *(float4*)(&sg[nl * HPAD + jq]) = gq;
    __syncthreads();

    float c0 = sb2[jq], c1 = sb2[jq + 1], c2 = sb2[jq + 2], c3 = sb2[jq + 3];
#pragma unroll
    for (int k0 = 0; k0 < FDIM; k0 += 4) {
        float4 gv = *(float4*)(&sg[nl * HPAD + k0]);
        float4 w0 = *(float4*)(&sW2[(k0 + 0) * FDIM + jq]);
        float4 w1 = *(float4*)(&sW2[(k0 + 1) * FDIM + jq]);
        float4 w2 = *(float4*)(&sW2[(k0 + 2) * FDIM + jq]);
        float4 w3 = *(float4*)(&sW2[(k0 + 3) * FDIM + jq]);
        c0 += gv.x * w0.x + gv.y * w1.x + gv.z * w2.x + gv.w * w3.x;
        c1 += gv.x * w0.y + gv.y * w1.y + gv.z * w2.y + gv.w * w3.y;
        c2 += gv.x * w0.z + gv.y * w1.z + gv.z * w2.z + gv.w * w3.z;
        c3 += gv.x * w0.w + gv.y * w1.w + gv.z * w2.w + gv.w * w3.w;
    }
    float4 o;
    o.x = fmaxf(c0, 0.f); o.y = fmaxf(c1, 0.f);
    o.z = fmaxf(c2, 0.f); o.w = fmaxf(c3, 0.f);
    *(float4*)(y + (size_t)(base + nl) * FDIM + jq) = o;
}

// out = x @ W_lin + b_lin ; W_lin is (64,10) row-major
__global__ __launch_bounds__(256) void final_linear(const float* __restrict__ x,
                                                    const float* __restrict__ W,
                                                    const float* __restrict__ b,
                                                    float* __restrict__ out, int n_nodes) {
    __shared__ float sW[FDIM * 10];
    __shared__ float sb[10];
    for (int i = threadIdx.x; i < FDIM * 10; i += 256) sW[i] = W[i];
    if (threadIdx.x < 10) sb[threadIdx.x] = b[threadIdx.x];
    __syncthreads();
    int node = blockIdx.x * 256 + threadIdx.x;
    if (node >= n_nodes) return;

    float h[FDIM];
    const float4* xp = (const float4*)(x + (size_t)node * FDIM);
#pragma unroll
    for (int k = 0; k < FDIM / 4; k++) {
        float4 v = xp[k];
        h[4 * k + 0] = v.x; h[4 * k + 1] = v.y;
        h[4 * k + 2] = v.z; h[4 * k + 3] = v.w;
    }
    float acc[10];
#pragma unroll
    for (int c = 0; c < 10; c++) acc[c] = sb[c];
    for (int k = 0; k < FDIM; k++) {
        float w = h[k];
#pragma unroll
        for (int c = 0; c < 10; c++) acc[c] += w * sW[k * 10 + c];
    }
    float* op = out + (size_t)node * 10;
#pragma unroll
    for (int c = 0; c < 10; c++) op[c] = acc[c];
}

extern "C" void kernel_launch(void* const* d_in, const int* in_sizes, int n_in,
                              void* d_out, int out_size, void* d_ws, size_t ws_size,
                              hipStream_t stream) {
    const float* features = (const float*)d_in[0];
    const int* edges = (const int*)d_in[1];
    int n_nodes = in_sizes[0] / FDIM;          // 50000
    int n_edges = in_sizes[1] / 2;             // 800000
    const int* src = edges;
    const int* dst = edges + n_edges;

    int nbuck = (n_nodes + BNODES - 1) / BNODES;     // 782  (<=1024)
    int nchunks = (n_edges + CHUNK - 1) / CHUNK;     // 98   (<=256)

    // workspace: hist | chunk_off | bucket_total | bucket_start | row_ptr | packed | src_sorted | h | xA | xB
    int* hist = (int*)d_ws;
    int* chunk_off = hist + (size_t)nchunks * nbuck;
    int* bucket_total = chunk_off + (size_t)nchunks * nbuck;
    int* bucket_start = bucket_total + nbuck;
    int* row_ptr = bucket_start + nbuck + 1;
    unsigned int* packed = (unsigned int*)(row_ptr + n_nodes + 1);
    int* src_sorted = (int*)(packed + n_edges);
    size_t int_elems = 2 * (size_t)nchunks * nbuck + 2 * (size_t)nbuck + 2
                       + (size_t)n_nodes + 2 * (size_t)n_edges;
    int_elems = (int_elems + 3) & ~(size_t)3;
    float* h  = (float*)d_ws + int_elems;
    size_t buf_elems = (size_t)n_nodes * FDIM;
    float* xA = h + buf_elems;
    float* xB = xA + buf_elems;

    dim3 bs(256);
    dim3 gs_gather((n_nodes * 16 + 255) / 256);
    dim3 gs_node((n_nodes + 255) / 256);
    dim3 gs_mlp(n_nodes / 16);  // 3125, exact

    // --- build node-grouped CSR via 2-pass bucket sort ---
    bucket_hist<<<nchunks, 256, 0, stream>>>(dst, hist, n_edges, nbuck);
    scan_chunks<<<nbuck, 256, 0, stream>>>(hist, chunk_off, bucket_total, nchunks, nbuck);
    scan_buckets<<<1, 1024, 0, stream>>>(bucket_total, bucket_start, row_ptr, nbuck, n_nodes, n_edges);
    bucket_fill<<<nchunks, 256, 0, stream>>>(src, dst, bucket_start, chunk_off, packed, n_edges, nbuck);
    sort_bucket<<<nbuck, 256, 0, stream>>>(packed, bucket_start, src_sorted, row_ptr, n_nodes);

    // --- 3 GIN convs ---
    const float* x_cur = features;
    float* outs[3] = {xA, xB, xA};
    for (int conv = 0; conv < 3; conv++) {
        const float* W1 = (const float*)d_in[2 + 4 * conv];
        const float* b1 = (const float*)d_in[3 + 4 * conv];
        const float* W2 = (const float*)d_in[4 + 4 * conv];
        const float* b2 = (const float*)d_in[5 + 4 * conv];

        gather_nodes<<<gs_gather, bs, 0, stream>>>(x_cur, row_ptr, src_sorted, h, n_nodes);
        mlp_relu2<<<gs_mlp, bs, 0, stream>>>(h, W1, b1, W2, b2, outs[conv], n_nodes);
        x_cur = outs[conv];
    }

    const float* W_lin = (const float*)d_in[14];
    const float* b_lin = (const float*)d_in[15];
    final_linear<<<gs_node, bs, 0, stream>>>(x_cur, W_lin, b_lin, (float*)d_out, n_nodes);
}

// Round 6
// 307.060 us; speedup vs baseline: 3.8850x; 1.0319x over previous
//
#include <hip/hip_runtime.h>
#include <hip/hip_bf16.h>

#define FDIM 64
#define BNODES 64          // nodes per bucket (dst >> 6)
#define CHUNK 8192         // edges per partition chunk
#define HPAD 68            // padded LDS row

// ---- pass 1: per-chunk bucket histogram (LDS) ----
__global__ __launch_bounds__(256) void bucket_hist(const int* __restrict__ dst,
                                                   int* __restrict__ hist,
                                                   int n_edges, int nbuck) {
    __shared__ int lh[1024];               // nbuck <= 1024
    int chunk = blockIdx.x;
    for (int i = threadIdx.x; i < nbuck; i += 256) lh[i] = 0;
    __syncthreads();
    int beg = chunk * CHUNK;
    int end = min(beg + CHUNK, n_edges);
    for (int e = beg + threadIdx.x; e < end; e += 256)
        atomicAdd(&lh[dst[e] >> 6], 1);
    __syncthreads();
    for (int i = threadIdx.x; i < nbuck; i += 256)
        hist[(size_t)chunk * nbuck + i] = lh[i];
}

// ---- pass 2a: per-bucket exclusive scan over chunks ----
__global__ __launch_bounds__(256) void scan_chunks(const int* __restrict__ hist,
                                                   int* __restrict__ chunk_off,
                                                   int* __restrict__ bucket_total,
                                                   int nchunks, int nbuck) {
    __shared__ int s[256];                 // nchunks <= 256
    int b = blockIdx.x;
    int t = threadIdx.x;
    int v = (t < nchunks) ? hist[(size_t)t * nbuck + b] : 0;
    s[t] = v;
    __syncthreads();
    for (int off = 1; off < 256; off <<= 1) {
        int u = (t >= off) ? s[t - off] : 0;
        __syncthreads();
        s[t] += u;
        __syncthreads();
    }
    if (t < nchunks) chunk_off[(size_t)t * nbuck + b] = s[t] - v;  // exclusive
    if (t == 255) bucket_total[b] = s[255];
}

// ---- pass 2b: exclusive scan of bucket totals ----
__global__ __launch_bounds__(1024) void scan_buckets(const int* __restrict__ bucket_total,
                                                     int* __restrict__ bucket_start,
                                                     int* __restrict__ row_ptr,
                                                     int nbuck, int n_nodes, int n_edges) {
    __shared__ int s[1024];                // nbuck <= 1024
    int t = threadIdx.x;
    int v = (t < nbuck) ? bucket_total[t] : 0;
    s[t] = v;
    __syncthreads();
    for (int off = 1; off < 1024; off <<= 1) {
        int u = (t >= off) ? s[t - off] : 0;
        __syncthreads();
        s[t] += u;
        __syncthreads();
    }
    if (t < nbuck) bucket_start[t] = s[t] - v;
    if (t == 0) { bucket_start[nbuck] = n_edges; row_ptr[n_nodes] = n_edges; }
}

// ---- pass 3: fill packed edges, (chunk,bucket)-contiguous runs ----
__global__ __launch_bounds__(256) void bucket_fill(const int* __restrict__ src,
                                                   const int* __restrict__ dst,
                                                   const int* __restrict__ bucket_start,
                                                   const int* __restrict__ chunk_off,
                                                   unsigned int* __restrict__ packed,
                                                   int n_edges, int nbuck) {
    __shared__ int cur[1024];
    int chunk = blockIdx.x;
    for (int i = threadIdx.x; i < nbuck; i += 256)
        cur[i] = bucket_start[i] + chunk_off[(size_t)chunk * nbuck + i];
    __syncthreads();
    int beg = chunk * CHUNK;
    int end = min(beg + CHUNK, n_edges);
    for (int e = beg + threadIdx.x; e < end; e += 256) {
        int d = dst[e];
        int b = d >> 6;
        int pos = atomicAdd(&cur[b], 1);
        packed[pos] = (unsigned int)src[e] | ((unsigned int)(d & 63) << 16);
    }
}

// ---- pass 4: within-bucket sort to node granularity + row_ptr emit ----
__global__ __launch_bounds__(256) void sort_bucket(const unsigned int* __restrict__ packed,
                                                   const int* __restrict__ bucket_start,
                                                   int* __restrict__ src_sorted,
                                                   int* __restrict__ row_ptr, int n_nodes) {
    __shared__ int cnt[BNODES];
    __shared__ int cur[BNODES];
    int b = blockIdx.x;
    int beg = bucket_start[b], end = bucket_start[b + 1];
    if (threadIdx.x < BNODES) cnt[threadIdx.x] = 0;
    __syncthreads();
    for (int e = beg + threadIdx.x; e < end; e += 256)
        atomicAdd(&cnt[packed[e] >> 16], 1);
    __syncthreads();
    if (threadIdx.x == 0) {
        int run = beg;
        for (int i = 0; i < BNODES; i++) { cur[i] = run; run += cnt[i]; }
    }
    __syncthreads();
    if (threadIdx.x < BNODES) {
        int node = b * BNODES + threadIdx.x;
        if (node < n_nodes) row_ptr[node] = cur[threadIdx.x];
    }
    __syncthreads();
    for (int e = beg + threadIdx.x; e < end; e += 256) {
        unsigned int p = packed[e];
        int pos = atomicAdd(&cur[p >> 16], 1);
        src_sorted[pos] = (int)(p & 0xFFFFu);
    }
}

// gather: h[n] = x[n] + sum_{e in row} x[src_sorted[e]] ; 16 threads/node, 4x unroll
__global__ __launch_bounds__(256) void gather_nodes(const float* __restrict__ x,
                                                    const int* __restrict__ row_ptr,
                                                    const int* __restrict__ src_sorted,
                                                    float* __restrict__ h, int n_nodes) {
    int t = blockIdx.x * blockDim.x + threadIdx.x;
    int node = t >> 4;
    if (node >= n_nodes) return;
    int c = (t & 15) * 4;
    int beg = row_ptr[node];
    int end = row_ptr[node + 1];
    float4 acc = *(const float4*)(x + (size_t)node * FDIM + c);
    int e = beg;
    for (; e + 3 < end; e += 4) {
        int s0 = src_sorted[e];
        int s1 = src_sorted[e + 1];
        int s2 = src_sorted[e + 2];
        int s3 = src_sorted[e + 3];
        float4 v0 = *(const float4*)(x + (size_t)s0 * FDIM + c);
        float4 v1 = *(const float4*)(x + (size_t)s1 * FDIM + c);
        float4 v2 = *(const float4*)(x + (size_t)s2 * FDIM + c);
        float4 v3 = *(const float4*)(x + (size_t)s3 * FDIM + c);
        acc.x += (v0.x + v1.x) + (v2.x + v3.x);
        acc.y += (v0.y + v1.y) + (v2.y + v3.y);
        acc.z += (v0.z + v1.z) + (v2.z + v3.z);
        acc.w += (v0.w + v1.w) + (v2.w + v3.w);
    }
    for (; e < end; e++) {
        int s0 = src_sorted[e];
        float4 v0 = *(const float4*)(x + (size_t)s0 * FDIM + c);
        acc.x += v0.x; acc.y += v0.y; acc.z += v0.z; acc.w += v0.w;
    }
    *(float4*)(h + (size_t)node * FDIM + c) = acc;
}

// MLP over a 64-node tile, 4 nodes per thread (register-blocked).
// thread t: ng = t>>4 handles node rows ng*4..ng*4+3, jq = (t&15)*4 output quad.
// sh buffer reused: h -> g -> o. Optionally fuses the final 64->10 linear.
__global__ __launch_bounds__(256) void mlp_tile(const float* __restrict__ x,
        const float* __restrict__ W1, const float* __restrict__ b1,
        const float* __restrict__ W2, const float* __restrict__ b2,
        const float* __restrict__ Wl, const float* __restrict__ bl,
        float* __restrict__ y, float* __restrict__ out,
        int n_nodes, int do_final) {
    __shared__ float sW1[FDIM * FDIM];
    __shared__ float sW2[FDIM * FDIM];
    __shared__ float sh[64 * HPAD];
    __shared__ float sb1[FDIM], sb2[FDIM];
    __shared__ float sWl[FDIM * 10];
    __shared__ float sbl[16];

    int tid = threadIdx.x;
    int base = blockIdx.x * 64;

    // stage weights: 4096 floats each = 1024 float4, 4 per thread
    {
        const float4* W14 = (const float4*)W1;
        const float4* W24 = (const float4*)W2;
        float4* s1 = (float4*)sW1;
        float4* s2 = (float4*)sW2;
#pragma unroll
        for (int k = 0; k < 4; k++) {
            s1[tid + k * 256] = W14[tid + k * 256];
            s2[tid + k * 256] = W24[tid + k * 256];
        }
    }
    if (tid < FDIM) { sb1[tid] = b1[tid]; sb2[tid] = b2[tid]; }
    if (do_final) {
        for (int i = tid; i < FDIM * 10; i += 256) sWl[i] = Wl[i];
        if (tid < 10) sbl[tid] = bl[tid];
    }
    // stage h tile: 64 rows x 16 float4, 4 per thread, coalesced
    {
#pragma unroll
        for (int k = 0; k < 4; k++) {
            int idx = tid + k * 256;
            int r = idx >> 4, c4 = (idx & 15) * 4;
            int node = base + r;
            float4 v = make_float4(0.f, 0.f, 0.f, 0.f);
            if (node < n_nodes) v = *(const float4*)(x + (size_t)node * FDIM + c4);
            *(float4*)(&sh[r * HPAD + c4]) = v;
        }
    }
    __syncthreads();

    int ng = tid >> 4;
    int jq = (tid & 15) * 4;
    int r0 = ng * 4;

    float a[4][4];
    // ---- layer 1: g = relu(h @ W1 + b1) ----
#pragma unroll
    for (int i = 0; i < 4; i++) {
        a[i][0] = sb1[jq]; a[i][1] = sb1[jq + 1];
        a[i][2] = sb1[jq + 2]; a[i][3] = sb1[jq + 3];
    }
#pragma unroll
    for (int k0 = 0; k0 < FDIM; k0 += 4) {
        float4 w0 = *(float4*)(&sW1[(k0 + 0) * FDIM + jq]);
        float4 w1 = *(float4*)(&sW1[(k0 + 1) * FDIM + jq]);
        float4 w2 = *(float4*)(&sW1[(k0 + 2) * FDIM + jq]);
        float4 w3 = *(float4*)(&sW1[(k0 + 3) * FDIM + jq]);
#pragma unroll
        for (int i = 0; i < 4; i++) {
            float4 hv = *(float4*)(&sh[(r0 + i) * HPAD + k0]);
            a[i][0] += hv.x * w0.x + hv.y * w1.x + hv.z * w2.x + hv.w * w3.x;
            a[i][1] += hv.x * w0.y + hv.y * w1.y + hv.z * w2.y + hv.w * w3.y;
            a[i][2] += hv.x * w0.z + hv.y * w1.z + hv.z * w2.z + hv.w * w3.z;
            a[i][3] += hv.x * w0.w + hv.y * w1.w + hv.z * w2.w + hv.w * w3.w;
        }
    }
    __syncthreads();   // all h reads done; sh is free
#pragma unroll
    for (int i = 0; i < 4; i++) {
        float4 g;
        g.x = fmaxf(a[i][0], 0.f); g.y = fmaxf(a[i][1], 0.f);
        g.z = fmaxf(a[i][2], 0.f); g.w = fmaxf(a[i][3], 0.f);
        *(float4*)(&sh[(r0 + i) * HPAD + jq]) = g;
    }
    __syncthreads();

    // ---- layer 2: o = relu(g @ W2 + b2) ----
#pragma unroll
    for (int i = 0; i < 4; i++) {
        a[i][0] = sb2[jq]; a[i][1] = sb2[jq + 1];
        a[i][2] = sb2[jq + 2]; a[i][3] = sb2[jq + 3];
    }
#pragma unroll
    for (int k0 = 0; k0 < FDIM; k0 += 4) {
        float4 w0 = *(float4*)(&sW2[(k0 + 0) * FDIM + jq]);
        float4 w1 = *(float4*)(&sW2[(k0 + 1) * FDIM + jq]);
        float4 w2 = *(float4*)(&sW2[(k0 + 2) * FDIM + jq]);
        float4 w3 = *(float4*)(&sW2[(k0 + 3) * FDIM + jq]);
#pragma unroll
        for (int i = 0; i < 4; i++) {
            float4 gv = *(float4*)(&sh[(r0 + i) * HPAD + k0]);
            a[i][0] += gv.x * w0.x + gv.y * w1.x + gv.z * w2.x + gv.w * w3.x;
            a[i][1] += gv.x * w0.y + gv.y * w1.y + gv.z * w2.y + gv.w * w3.y;
            a[i][2] += gv.x * w0.z + gv.y * w1.z + gv.z * w2.z + gv.w * w3.z;
            a[i][3] += gv.x * w0.w + gv.y * w1.w + gv.z * w2.w + gv.w * w3.w;
        }
    }

    if (!do_final) {
#pragma unroll
        for (int i = 0; i < 4; i++) {
            int node = base + r0 + i;
            if (node < n_nodes) {
                float4 o;
                o.x = fmaxf(a[i][0], 0.f); o.y = fmaxf(a[i][1], 0.f);
                o.z = fmaxf(a[i][2], 0.f); o.w = fmaxf(a[i][3], 0.f);
                *(float4*)(y + (size_t)node * FDIM + jq) = o;
            }
        }
    } else {
        __syncthreads();   // all g reads done; sh free again
#pragma unroll
        for (int i = 0; i < 4; i++) {
            float4 o;
            o.x = fmaxf(a[i][0], 0.f); o.y = fmaxf(a[i][1], 0.f);
            o.z = fmaxf(a[i][2], 0.f); o.w = fmaxf(a[i][3], 0.f);
            *(float4*)(&sh[(r0 + i) * HPAD + jq]) = o;
        }
        __syncthreads();
        // final linear: 64 nodes x 10 classes = 640 outputs
        for (int i = tid; i < 64 * 10; i += 256) {
            int nl = i / 10, c = i % 10;
            int node = base + nl;
            if (node < n_nodes) {
                float acc = sbl[c];
#pragma unroll
                for (int k0 = 0; k0 < FDIM; k0 += 4) {
                    float4 hv = *(float4*)(&sh[nl * HPAD + k0]);
                    acc += hv.x * sWl[(k0 + 0) * 10 + c] + hv.y * sWl[(k0 + 1) * 10 + c]
                         + hv.z * sWl[(k0 + 2) * 10 + c] + hv.w * sWl[(k0 + 3) * 10 + c];
                }
                out[(size_t)node * 10 + c] = acc;
            }
        }
    }
}

extern "C" void kernel_launch(void* const* d_in, const int* in_sizes, int n_in,
                              void* d_out, int out_size, void* d_ws, size_t ws_size,
                              hipStream_t stream) {
    const float* features = (const float*)d_in[0];
    const int* edges = (const int*)d_in[1];
    int n_nodes = in_sizes[0] / FDIM;          // 50000
    int n_edges = in_sizes[1] / 2;             // 800000
    const int* src = edges;
    const int* dst = edges + n_edges;

    int nbuck = (n_nodes + BNODES - 1) / BNODES;     // 782  (<=1024)
    int nchunks = (n_edges + CHUNK - 1) / CHUNK;     // 98   (<=256)

    // workspace: hist | chunk_off | bucket_total | bucket_start | row_ptr | packed | src_sorted | h | xA | xB
    int* hist = (int*)d_ws;
    int* chunk_off = hist + (size_t)nchunks * nbuck;
    int* bucket_total = chunk_off + (size_t)nchunks * nbuck;
    int* bucket_start = bucket_total + nbuck;
    int* row_ptr = bucket_start + nbuck + 1;
    unsigned int* packed = (unsigned int*)(row_ptr + n_nodes + 1);
    int* src_sorted = (int*)(packed + n_edges);
    size_t int_elems = 2 * (size_t)nchunks * nbuck + 2 * (size_t)nbuck + 2
                       + (size_t)n_nodes + 2 * (size_t)n_edges;
    int_elems = (int_elems + 3) & ~(size_t)3;
    float* h  = (float*)d_ws + int_elems;
    size_t buf_elems = (size_t)n_nodes * FDIM;
    float* xA = h + buf_elems;
    float* xB = xA + buf_elems;

    dim3 bs(256);
    dim3 gs_gather((n_nodes * 16 + 255) / 256);
    dim3 gs_tile((n_nodes + 63) / 64);   // 782

    // --- build node-grouped CSR via 2-pass bucket sort ---
    bucket_hist<<<nchunks, 256, 0, stream>>>(dst, hist, n_edges, nbuck);
    scan_chunks<<<nbuck, 256, 0, stream>>>(hist, chunk_off, bucket_total, nchunks, nbuck);
    scan_buckets<<<1, 1024, 0, stream>>>(bucket_total, bucket_start, row_ptr, nbuck, n_nodes, n_edges);
    bucket_fill<<<nchunks, 256, 0, stream>>>(src, dst, bucket_start, chunk_off, packed, n_edges, nbuck);
    sort_bucket<<<nbuck, 256, 0, stream>>>(packed, bucket_start, src_sorted, row_ptr, n_nodes);

    // --- 3 GIN convs (last one fuses the final linear) ---
    const float* Wl = (const float*)d_in[14];
    const float* bl = (const float*)d_in[15];
    const float* x_cur = features;
    float* outs[3] = {xA, xB, xA};
    for (int conv = 0; conv < 3; conv++) {
        const float* W1 = (const float*)d_in[2 + 4 * conv];
        const float* b1 = (const float*)d_in[3 + 4 * conv];
        const float* W2 = (const float*)d_in[4 + 4 * conv];
        const float* b2 = (const float*)d_in[5 + 4 * conv];
        int fin = (conv == 2) ? 1 : 0;

        gather_nodes<<<gs_gather, bs, 0, stream>>>(x_cur, row_ptr, src_sorted, h, n_nodes);
        mlp_tile<<<gs_tile, bs, 0, stream>>>(h, W1, b1, W2, b2, Wl, bl,
                                             outs[conv], (float*)d_out, n_nodes, fin);
        x_cur = outs[conv];
    }
}

// Round 7
// 274.251 us; speedup vs baseline: 4.3498x; 1.1196x over previous
//
#include <hip/hip_runtime.h>
#include <hip/hip_bf16.h>

#define FDIM 64
#define BNODES 64          // nodes per bucket (dst >> 6)
#define CHUNK 8192         // edges per partition chunk
#define HPAD 68            // padded LDS row

__device__ __forceinline__ unsigned short f2bf(float f) {
    unsigned int u = __float_as_uint(f);
    unsigned int r = (u + 0x7fffu + ((u >> 16) & 1u)) >> 16;   // RNE
    return (unsigned short)r;
}
__device__ __forceinline__ float bflo(unsigned int p) { return __uint_as_float(p << 16); }
__device__ __forceinline__ float bfhi(unsigned int p) { return __uint_as_float(p & 0xffff0000u); }

// ---- cast fp32 -> bf16 (features), 4 elems/thread ----
__global__ __launch_bounds__(256) void cast_bf16(const float* __restrict__ x,
                                                 unsigned short* __restrict__ xb, int n4) {
    int i = blockIdx.x * blockDim.x + threadIdx.x;
    if (i < n4) {
        float4 v = ((const float4*)x)[i];
        uint2 o;
        o.x = (unsigned int)f2bf(v.x) | ((unsigned int)f2bf(v.y) << 16);
        o.y = (unsigned int)f2bf(v.z) | ((unsigned int)f2bf(v.w) << 16);
        ((uint2*)xb)[i] = o;
    }
}

// ---- pass 1: per-chunk bucket histogram (LDS) ----
__global__ __launch_bounds__(256) void bucket_hist(const int* __restrict__ dst,
                                                   int* __restrict__ hist,
                                                   int n_edges, int nbuck) {
    __shared__ int lh[1024];               // nbuck <= 1024
    int chunk = blockIdx.x;
    for (int i = threadIdx.x; i < nbuck; i += 256) lh[i] = 0;
    __syncthreads();
    int beg = chunk * CHUNK;
    int end = min(beg + CHUNK, n_edges);
    for (int e = beg + threadIdx.x; e < end; e += 256)
        atomicAdd(&lh[dst[e] >> 6], 1);
    __syncthreads();
    for (int i = threadIdx.x; i < nbuck; i += 256)
        hist[(size_t)chunk * nbuck + i] = lh[i];
}

// ---- pass 2a: per-bucket exclusive scan over chunks ----
__global__ __launch_bounds__(256) void scan_chunks(const int* __restrict__ hist,
                                                   int* __restrict__ chunk_off,
                                                   int* __restrict__ bucket_total,
                                                   int nchunks, int nbuck) {
    __shared__ int s[256];                 // nchunks <= 256
    int b = blockIdx.x;
    int t = threadIdx.x;
    int v = (t < nchunks) ? hist[(size_t)t * nbuck + b] : 0;
    s[t] = v;
    __syncthreads();
    for (int off = 1; off < 256; off <<= 1) {
        int u = (t >= off) ? s[t - off] : 0;
        __syncthreads();
        s[t] += u;
        __syncthreads();
    }
    if (t < nchunks) chunk_off[(size_t)t * nbuck + b] = s[t] - v;  // exclusive
    if (t == 255) bucket_total[b] = s[255];
}

// ---- pass 2b: exclusive scan of bucket totals ----
__global__ __launch_bounds__(1024) void scan_buckets(const int* __restrict__ bucket_total,
                                                     int* __restrict__ bucket_start,
                                                     int* __restrict__ row_ptr,
                                                     int nbuck, int n_nodes, int n_edges) {
    __shared__ int s[1024];                // nbuck <= 1024
    int t = threadIdx.x;
    int v = (t < nbuck) ? bucket_total[t] : 0;
    s[t] = v;
    __syncthreads();
    for (int off = 1; off < 1024; off <<= 1) {
        int u = (t >= off) ? s[t - off] : 0;
        __syncthreads();
        s[t] += u;
        __syncthreads();
    }
    if (t < nbuck) bucket_start[t] = s[t] - v;
    if (t == 0) { bucket_start[nbuck] = n_edges; row_ptr[n_nodes] = n_edges; }
}

// ---- pass 3: fill packed edges, (chunk,bucket)-contiguous runs ----
__global__ __launch_bounds__(256) void bucket_fill(const int* __restrict__ src,
                                                   const int* __restrict__ dst,
                                                   const int* __restrict__ bucket_start,
                                                   const int* __restrict__ chunk_off,
                                                   unsigned int* __restrict__ packed,
                                                   int n_edges, int nbuck) {
    __shared__ int cur[1024];
    int chunk = blockIdx.x;
    for (int i = threadIdx.x; i < nbuck; i += 256)
        cur[i] = bucket_start[i] + chunk_off[(size_t)chunk * nbuck + i];
    __syncthreads();
    int beg = chunk * CHUNK;
    int end = min(beg + CHUNK, n_edges);
    for (int e = beg + threadIdx.x; e < end; e += 256) {
        int d = dst[e];
        int b = d >> 6;
        int pos = atomicAdd(&cur[b], 1);
        packed[pos] = (unsigned int)src[e] | ((unsigned int)(d & 63) << 16);
    }
}

// ---- pass 4: within-bucket sort to node granularity + row_ptr emit ----
__global__ __launch_bounds__(256) void sort_bucket(const unsigned int* __restrict__ packed,
                                                   const int* __restrict__ bucket_start,
                                                   int* __restrict__ src_sorted,
                                                   int* __restrict__ row_ptr, int n_nodes) {
    __shared__ int cnt[BNODES];
    __shared__ int cur[BNODES];
    int b = blockIdx.x;
    int beg = bucket_start[b], end = bucket_start[b + 1];
    if (threadIdx.x < BNODES) cnt[threadIdx.x] = 0;
    __syncthreads();
    for (int e = beg + threadIdx.x; e < end; e += 256)
        atomicAdd(&cnt[packed[e] >> 16], 1);
    __syncthreads();
    if (threadIdx.x == 0) {
        int run = beg;
        for (int i = 0; i < BNODES; i++) { cur[i] = run; run += cnt[i]; }
    }
    __syncthreads();
    if (threadIdx.x < BNODES) {
        int node = b * BNODES + threadIdx.x;
        if (node < n_nodes) row_ptr[node] = cur[threadIdx.x];
    }
    __syncthreads();
    for (int e = beg + threadIdx.x; e < end; e += 256) {
        unsigned int p = packed[e];
        int pos = atomicAdd(&cur[p >> 16], 1);
        src_sorted[pos] = (int)(p & 0xFFFFu);
    }
}

// gather from bf16 rows: h[n] = x[n] + sum x[src]; 16 threads/node (4 feats each), fp32 accum
__global__ __launch_bounds__(256) void gather_bf16(const unsigned short* __restrict__ xb,
                                                   const int* __restrict__ row_ptr,
                                                   const int* __restrict__ src_sorted,
                                                   float* __restrict__ h, int n_nodes) {
    int t = blockIdx.x * blockDim.x + threadIdx.x;
    int node = t >> 4;
    if (node >= n_nodes) return;
    int c = (t & 15) * 4;
    int beg = row_ptr[node];
    int end = row_ptr[node + 1];
    float4 acc;
    {
        uint2 v = *(const uint2*)(xb + (size_t)node * FDIM + c);
        acc.x = bflo(v.x); acc.y = bfhi(v.x);
        acc.z = bflo(v.y); acc.w = bfhi(v.y);
    }
    int e = beg;
    for (; e + 3 < end; e += 4) {
        int s0 = src_sorted[e];
        int s1 = src_sorted[e + 1];
        int s2 = src_sorted[e + 2];
        int s3 = src_sorted[e + 3];
        uint2 v0 = *(const uint2*)(xb + (size_t)s0 * FDIM + c);
        uint2 v1 = *(const uint2*)(xb + (size_t)s1 * FDIM + c);
        uint2 v2 = *(const uint2*)(xb + (size_t)s2 * FDIM + c);
        uint2 v3 = *(const uint2*)(xb + (size_t)s3 * FDIM + c);
        acc.x += (bflo(v0.x) + bflo(v1.x)) + (bflo(v2.x) + bflo(v3.x));
        acc.y += (bfhi(v0.x) + bfhi(v1.x)) + (bfhi(v2.x) + bfhi(v3.x));
        acc.z += (bflo(v0.y) + bflo(v1.y)) + (bflo(v2.y) + bflo(v3.y));
        acc.w += (bfhi(v0.y) + bfhi(v1.y)) + (bfhi(v2.y) + bfhi(v3.y));
    }
    for (; e < end; e++) {
        int s0 = src_sorted[e];
        uint2 v0 = *(const uint2*)(xb + (size_t)s0 * FDIM + c);
        acc.x += bflo(v0.x); acc.y += bfhi(v0.x);
        acc.z += bflo(v0.y); acc.w += bfhi(v0.y);
    }
    *(float4*)(h + (size_t)node * FDIM + c) = acc;
}

// MLP over a 64-node tile, 4 nodes/thread register-blocked; fp32 math.
// Output: bf16 rows (for the next gather), or fused final 64->10 fp32 linear.
__global__ __launch_bounds__(256) void mlp_tile(const float* __restrict__ x,
        const float* __restrict__ W1, const float* __restrict__ b1,
        const float* __restrict__ W2, const float* __restrict__ b2,
        const float* __restrict__ Wl, const float* __restrict__ bl,
        unsigned short* __restrict__ y, float* __restrict__ out,
        int n_nodes, int do_final) {
    __shared__ float sW1[FDIM * FDIM];
    __shared__ float sW2[FDIM * FDIM];
    __shared__ float sh[64 * HPAD];
    __shared__ float sb1[FDIM], sb2[FDIM];
    __shared__ float sWl[FDIM * 10];
    __shared__ float sbl[16];

    int tid = threadIdx.x;
    int base = blockIdx.x * 64;

    {
        const float4* W14 = (const float4*)W1;
        const float4* W24 = (const float4*)W2;
        float4* s1 = (float4*)sW1;
        float4* s2 = (float4*)sW2;
#pragma unroll
        for (int k = 0; k < 4; k++) {
            s1[tid + k * 256] = W14[tid + k * 256];
            s2[tid + k * 256] = W24[tid + k * 256];
        }
    }
    if (tid < FDIM) { sb1[tid] = b1[tid]; sb2[tid] = b2[tid]; }
    if (do_final) {
        for (int i = tid; i < FDIM * 10; i += 256) sWl[i] = Wl[i];
        if (tid < 10) sbl[tid] = bl[tid];
    }
    {
#pragma unroll
        for (int k = 0; k < 4; k++) {
            int idx = tid + k * 256;
            int r = idx >> 4, c4 = (idx & 15) * 4;
            int node = base + r;
            float4 v = make_float4(0.f, 0.f, 0.f, 0.f);
            if (node < n_nodes) v = *(const float4*)(x + (size_t)node * FDIM + c4);
            *(float4*)(&sh[r * HPAD + c4]) = v;
        }
    }
    __syncthreads();

    int ng = tid >> 4;
    int jq = (tid & 15) * 4;
    int r0 = ng * 4;

    float a[4][4];
#pragma unroll
    for (int i = 0; i < 4; i++) {
        a[i][0] = sb1[jq]; a[i][1] = sb1[jq + 1];
        a[i][2] = sb1[jq + 2]; a[i][3] = sb1[jq + 3];
    }
#pragma unroll
    for (int k0 = 0; k0 < FDIM; k0 += 4) {
        float4 w0 = *(float4*)(&sW1[(k0 + 0) * FDIM + jq]);
        float4 w1 = *(float4*)(&sW1[(k0 + 1) * FDIM + jq]);
        float4 w2 = *(float4*)(&sW1[(k0 + 2) * FDIM + jq]);
        float4 w3 = *(float4*)(&sW1[(k0 + 3) * FDIM + jq]);
#pragma unroll
        for (int i = 0; i < 4; i++) {
            float4 hv = *(float4*)(&sh[(r0 + i) * HPAD + k0]);
            a[i][0] += hv.x * w0.x + hv.y * w1.x + hv.z * w2.x + hv.w * w3.x;
            a[i][1] += hv.x * w0.y + hv.y * w1.y + hv.z * w2.y + hv.w * w3.y;
            a[i][2] += hv.x * w0.z + hv.y * w1.z + hv.z * w2.z + hv.w * w3.z;
            a[i][3] += hv.x * w0.w + hv.y * w1.w + hv.z * w2.w + hv.w * w3.w;
        }
    }
    __syncthreads();
#pragma unroll
    for (int i = 0; i < 4; i++) {
        float4 g;
        g.x = fmaxf(a[i][0], 0.f); g.y = fmaxf(a[i][1], 0.f);
        g.z = fmaxf(a[i][2], 0.f); g.w = fmaxf(a[i][3], 0.f);
        *(float4*)(&sh[(r0 + i) * HPAD + jq]) = g;
    }
    __syncthreads();

#pragma unroll
    for (int i = 0; i < 4; i++) {
        a[i][0] = sb2[jq]; a[i][1] = sb2[jq + 1];
        a[i][2] = sb2[jq + 2]; a[i][3] = sb2[jq + 3];
    }
#pragma unroll
    for (int k0 = 0; k0 < FDIM; k0 += 4) {
        float4 w0 = *(float4*)(&sW2[(k0 + 0) * FDIM + jq]);
        float4 w1 = *(float4*)(&sW2[(k0 + 1) * FDIM + jq]);
        float4 w2 = *(float4*)(&sW2[(k0 + 2) * FDIM + jq]);
        float4 w3 = *(float4*)(&sW2[(k0 + 3) * FDIM + jq]);
#pragma unroll
        for (int i = 0; i < 4; i++) {
            float4 gv = *(float4*)(&sh[(r0 + i) * HPAD + k0]);
            a[i][0] += gv.x * w0.x + gv.y * w1.x + gv.z * w2.x + gv.w * w3.x;
            a[i][1] += gv.x * w0.y + gv.y * w1.y + gv.z * w2.y + gv.w * w3.y;
            a[i][2] += gv.x * w0.z + gv.y * w1.z + gv.z * w2.z + gv.w * w3.z;
            a[i][3] += gv.x * w0.w + gv.y * w1.w + gv.z * w2.w + gv.w * w3.w;
        }
    }

    if (!do_final) {
#pragma unroll
        for (int i = 0; i < 4; i++) {
            int node = base + r0 + i;
            if (node < n_nodes) {
                float o0 = fmaxf(a[i][0], 0.f), o1 = fmaxf(a[i][1], 0.f);
                float o2 = fmaxf(a[i][2], 0.f), o3 = fmaxf(a[i][3], 0.f);
                uint2 p;
                p.x = (unsigned int)f2bf(o0) | ((unsigned int)f2bf(o1) << 16);
                p.y = (unsigned int)f2bf(o2) | ((unsigned int)f2bf(o3) << 16);
                *(uint2*)(y + (size_t)node * FDIM + jq) = p;
            }
        }
    } else {
        __syncthreads();
#pragma unroll
        for (int i = 0; i < 4; i++) {
            float4 o;
            o.x = fmaxf(a[i][0], 0.f); o.y = fmaxf(a[i][1], 0.f);
            o.z = fmaxf(a[i][2], 0.f); o.w = fmaxf(a[i][3], 0.f);
            *(float4*)(&sh[(r0 + i) * HPAD + jq]) = o;
        }
        __syncthreads();
        for (int i = tid; i < 64 * 10; i += 256) {
            int nl = i / 10, c = i % 10;
            int node = base + nl;
            if (node < n_nodes) {
                float acc = sbl[c];
#pragma unroll
                for (int k0 = 0; k0 < FDIM; k0 += 4) {
                    float4 hv = *(float4*)(&sh[nl * HPAD + k0]);
                    acc += hv.x * sWl[(k0 + 0) * 10 + c] + hv.y * sWl[(k0 + 1) * 10 + c]
                         + hv.z * sWl[(k0 + 2) * 10 + c] + hv.w * sWl[(k0 + 3) * 10 + c];
                }
                out[(size_t)node * 10 + c] = acc;
            }
        }
    }
}

extern "C" void kernel_launch(void* const* d_in, const int* in_sizes, int n_in,
                              void* d_out, int out_size, void* d_ws, size_t ws_size,
                              hipStream_t stream) {
    const float* features = (const float*)d_in[0];
    const int* edges = (const int*)d_in[1];
    int n_nodes = in_sizes[0] / FDIM;          // 50000
    int n_edges = in_sizes[1] / 2;             // 800000
    const int* src = edges;
    const int* dst = edges + n_edges;

    int nbuck = (n_nodes + BNODES - 1) / BNODES;     // 782  (<=1024)
    int nchunks = (n_edges + CHUNK - 1) / CHUNK;     // 98   (<=256)

    // workspace: ints | h(fp32) | xb0,yA,yB (bf16)
    int* hist = (int*)d_ws;
    int* chunk_off = hist + (size_t)nchunks * nbuck;
    int* bucket_total = chunk_off + (size_t)nchunks * nbuck;
    int* bucket_start = bucket_total + nbuck;
    int* row_ptr = bucket_start + nbuck + 1;
    unsigned int* packed = (unsigned int*)(row_ptr + n_nodes + 1);
    int* src_sorted = (int*)(packed + n_edges);
    size_t int_elems = 2 * (size_t)nchunks * nbuck + 2 * (size_t)nbuck + 2
                       + (size_t)n_nodes + 2 * (size_t)n_edges;
    int_elems = (int_elems + 3) & ~(size_t)3;
    float* h = (float*)d_ws + int_elems;
    size_t buf_elems = (size_t)n_nodes * FDIM;
    unsigned short* xb0 = (unsigned short*)(h + buf_elems);
    unsigned short* yA = xb0 + buf_elems;
    unsigned short* yB = yA + buf_elems;

    dim3 bs(256);
    dim3 gs_cast(((int)(buf_elems / 4) + 255) / 256);
    dim3 gs_gather((n_nodes * 16 + 255) / 256);
    dim3 gs_tile((n_nodes + 63) / 64);   // 782

    // --- cast features to bf16 ---
    cast_bf16<<<gs_cast, bs, 0, stream>>>(features, xb0, (int)(buf_elems / 4));

    // --- build node-grouped CSR via 2-pass bucket sort ---
    bucket_hist<<<nchunks, 256, 0, stream>>>(dst, hist, n_edges, nbuck);
    scan_chunks<<<nbuck, 256, 0, stream>>>(hist, chunk_off, bucket_total, nchunks, nbuck);
    scan_buckets<<<1, 1024, 0, stream>>>(bucket_total, bucket_start, row_ptr, nbuck, n_nodes, n_edges);
    bucket_fill<<<nchunks, 256, 0, stream>>>(src, dst, bucket_start, chunk_off, packed, n_edges, nbuck);
    sort_bucket<<<nbuck, 256, 0, stream>>>(packed, bucket_start, src_sorted, row_ptr, n_nodes);

    // --- 3 GIN convs (last fuses the final linear) ---
    const float* Wl = (const float*)d_in[14];
    const float* bl = (const float*)d_in[15];
    const unsigned short* x_cur = xb0;
    unsigned short* outs[3] = {yA, yB, yA};
    for (int conv = 0; conv < 3; conv++) {
        const float* W1 = (const float*)d_in[2 + 4 * conv];
        const float* b1 = (const float*)d_in[3 + 4 * conv];
        const float* W2 = (const float*)d_in[4 + 4 * conv];
        const float* b2 = (const float*)d_in[5 + 4 * conv];
        int fin = (conv == 2) ? 1 : 0;

        gather_bf16<<<gs_gather, bs, 0, stream>>>(x_cur, row_ptr, src_sorted, h, n_nodes);
        mlp_tile<<<gs_tile, bs, 0, stream>>>(h, W1, b1, W2, b2, Wl, bl,
                                             outs[conv], (float*)d_out, n_nodes, fin);
        x_cur = outs[conv];
    }
}

// Round 8
// 252.744 us; speedup vs baseline: 4.7199x; 1.0851x over previous
//
#include <hip/hip_runtime.h>
#include <hip/hip_bf16.h>

#define FDIM 64
#define BNODES 64          // nodes per bucket (dst >> 6)
#define CHUNK 2048         // edges per partition chunk (391 chunks -> good CU usage)
#define HPAD 68            // padded LDS row
#define GCAP 768           // staged edge-index capacity per gather block (16 nodes, avg ~256)

__device__ __forceinline__ unsigned short f2bf(float f) {
    unsigned int u = __float_as_uint(f);
    unsigned int r = (u + 0x7fffu + ((u >> 16) & 1u)) >> 16;   // RNE
    return (unsigned short)r;
}
__device__ __forceinline__ float bflo(unsigned int p) { return __uint_as_float(p << 16); }
__device__ __forceinline__ float bfhi(unsigned int p) { return __uint_as_float(p & 0xffff0000u); }

// ---- cast fp32 -> bf16 (features), 4 elems/thread ----
__global__ __launch_bounds__(256) void cast_bf16(const float* __restrict__ x,
                                                 unsigned short* __restrict__ xb, int n4) {
    int i = blockIdx.x * blockDim.x + threadIdx.x;
    if (i < n4) {
        float4 v = ((const float4*)x)[i];
        uint2 o;
        o.x = (unsigned int)f2bf(v.x) | ((unsigned int)f2bf(v.y) << 16);
        o.y = (unsigned int)f2bf(v.z) | ((unsigned int)f2bf(v.w) << 16);
        ((uint2*)xb)[i] = o;
    }
}

// ---- pass 1: per-chunk bucket histogram (LDS) ----
__global__ __launch_bounds__(256) void bucket_hist(const int* __restrict__ dst,
                                                   int* __restrict__ hist,
                                                   int n_edges, int nbuck) {
    __shared__ int lh[1024];               // nbuck <= 1024
    int chunk = blockIdx.x;
    for (int i = threadIdx.x; i < nbuck; i += 256) lh[i] = 0;
    __syncthreads();
    int beg = chunk * CHUNK;
    int end = min(beg + CHUNK, n_edges);
    for (int e = beg + threadIdx.x; e < end; e += 256)
        atomicAdd(&lh[dst[e] >> 6], 1);
    __syncthreads();
    for (int i = threadIdx.x; i < nbuck; i += 256)
        hist[(size_t)chunk * nbuck + i] = lh[i];
}

// ---- pass 2a: per-bucket exclusive scan over chunks (nchunks <= 512) ----
__global__ __launch_bounds__(512) void scan_chunks(const int* __restrict__ hist,
                                                   int* __restrict__ chunk_off,
                                                   int* __restrict__ bucket_total,
                                                   int nchunks, int nbuck) {
    __shared__ int s[512];
    int b = blockIdx.x;
    int t = threadIdx.x;
    int v = (t < nchunks) ? hist[(size_t)t * nbuck + b] : 0;
    s[t] = v;
    __syncthreads();
    for (int off = 1; off < 512; off <<= 1) {
        int u = (t >= off) ? s[t - off] : 0;
        __syncthreads();
        s[t] += u;
        __syncthreads();
    }
    if (t < nchunks) chunk_off[(size_t)t * nbuck + b] = s[t] - v;  // exclusive
    if (t == 511) bucket_total[b] = s[511];
}

// ---- pass 2b: exclusive scan of bucket totals ----
__global__ __launch_bounds__(1024) void scan_buckets(const int* __restrict__ bucket_total,
                                                     int* __restrict__ bucket_start,
                                                     int* __restrict__ row_ptr,
                                                     int nbuck, int n_nodes, int n_edges) {
    __shared__ int s[1024];                // nbuck <= 1024
    int t = threadIdx.x;
    int v = (t < nbuck) ? bucket_total[t] : 0;
    s[t] = v;
    __syncthreads();
    for (int off = 1; off < 1024; off <<= 1) {
        int u = (t >= off) ? s[t - off] : 0;
        __syncthreads();
        s[t] += u;
        __syncthreads();
    }
    if (t < nbuck) bucket_start[t] = s[t] - v;
    if (t == 0) { bucket_start[nbuck] = n_edges; row_ptr[n_nodes] = n_edges; }
}

// ---- pass 3: fill packed edges, (chunk,bucket)-contiguous runs ----
__global__ __launch_bounds__(256) void bucket_fill(const int* __restrict__ src,
                                                   const int* __restrict__ dst,
                                                   const int* __restrict__ bucket_start,
                                                   const int* __restrict__ chunk_off,
                                                   unsigned int* __restrict__ packed,
                                                   int n_edges, int nbuck) {
    __shared__ int cur[1024];
    int chunk = blockIdx.x;
    for (int i = threadIdx.x; i < nbuck; i += 256)
        cur[i] = bucket_start[i] + chunk_off[(size_t)chunk * nbuck + i];
    __syncthreads();
    int beg = chunk * CHUNK;
    int end = min(beg + CHUNK, n_edges);
    for (int e = beg + threadIdx.x; e < end; e += 256) {
        int d = dst[e];
        int b = d >> 6;
        int pos = atomicAdd(&cur[b], 1);
        packed[pos] = (unsigned int)src[e] | ((unsigned int)(d & 63) << 16);
    }
}

// ---- pass 4: within-bucket sort to node granularity + row_ptr emit ----
__global__ __launch_bounds__(256) void sort_bucket(const unsigned int* __restrict__ packed,
                                                   const int* __restrict__ bucket_start,
                                                   int* __restrict__ src_sorted,
                                                   int* __restrict__ row_ptr, int n_nodes) {
    __shared__ int cnt[BNODES];
    __shared__ int cur[BNODES];
    int b = blockIdx.x;
    int beg = bucket_start[b], end = bucket_start[b + 1];
    if (threadIdx.x < BNODES) cnt[threadIdx.x] = 0;
    __syncthreads();
    for (int e = beg + threadIdx.x; e < end; e += 256)
        atomicAdd(&cnt[packed[e] >> 16], 1);
    __syncthreads();
    if (threadIdx.x < 64) {       // first wave: shfl inclusive scan over 64 degrees
        int v = cnt[threadIdx.x];
        int inc = v;
#pragma unroll
        for (int off = 1; off < 64; off <<= 1) {
            int u = __shfl_up(inc, off, 64);
            if (threadIdx.x >= off) inc += u;
        }
        cur[threadIdx.x] = beg + inc - v;     // exclusive
        int node = b * BNODES + threadIdx.x;
        if (node < n_nodes) row_ptr[node] = beg + inc - v;
    }
    __syncthreads();
    for (int e = beg + threadIdx.x; e < end; e += 256) {
        unsigned int p = packed[e];
        int pos = atomicAdd(&cur[p >> 16], 1);
        src_sorted[pos] = (int)(p & 0xFFFFu);
    }
}

// gather (bf16 in/out, fp32 accum): 16 nodes/block, 16 threads/node.
// Block's edge indices staged into LDS once (coalesced), removing the
// global index-load -> row-load dependency; rows unrolled 8-deep in flight.
__global__ __launch_bounds__(256) void gather_bf16(const unsigned short* __restrict__ xb,
                                                   const int* __restrict__ row_ptr,
                                                   const int* __restrict__ src_sorted,
                                                   unsigned short* __restrict__ hb,
                                                   int n_nodes) {
    __shared__ int sidx[GCAP];
    int base = blockIdx.x * 16;
    int ebeg = row_ptr[base];
    int eend = row_ptr[min(base + 16, n_nodes)];
    int total = eend - ebeg;
    int cnt = min(total, GCAP);
    for (int i = threadIdx.x; i < cnt; i += 256) sidx[i] = src_sorted[ebeg + i];
    __syncthreads();

    int t = threadIdx.x;
    int node = base + (t >> 4);
    if (node >= n_nodes) return;
    int c = (t & 15) * 4;
    int dbeg = row_ptr[node] - ebeg;
    int dend = row_ptr[node + 1] - ebeg;

    float4 acc;
    {
        uint2 v = *(const uint2*)(xb + (size_t)node * FDIM + c);
        acc.x = bflo(v.x); acc.y = bfhi(v.x);
        acc.z = bflo(v.y); acc.w = bfhi(v.y);
    }

    if (total <= GCAP) {          // fast path (virtually always)
        int e = dbeg;
        for (; e + 7 < dend; e += 8) {
            int s[8];
#pragma unroll
            for (int j = 0; j < 8; j++) s[j] = sidx[e + j];
            uint2 v[8];
#pragma unroll
            for (int j = 0; j < 8; j++) v[j] = *(const uint2*)(xb + (size_t)s[j] * FDIM + c);
#pragma unroll
            for (int j = 0; j < 8; j++) {
                acc.x += bflo(v[j].x); acc.y += bfhi(v[j].x);
                acc.z += bflo(v[j].y); acc.w += bfhi(v[j].y);
            }
        }
        if (e + 3 < dend) {
            int s[4];
#pragma unroll
            for (int j = 0; j < 4; j++) s[j] = sidx[e + j];
            uint2 v[4];
#pragma unroll
            for (int j = 0; j < 4; j++) v[j] = *(const uint2*)(xb + (size_t)s[j] * FDIM + c);
#pragma unroll
            for (int j = 0; j < 4; j++) {
                acc.x += bflo(v[j].x); acc.y += bfhi(v[j].x);
                acc.z += bflo(v[j].y); acc.w += bfhi(v[j].y);
            }
            e += 4;
        }
        for (; e < dend; e++) {
            uint2 v = *(const uint2*)(xb + (size_t)sidx[e] * FDIM + c);
            acc.x += bflo(v.x); acc.y += bfhi(v.x);
            acc.z += bflo(v.y); acc.w += bfhi(v.y);
        }
    } else {                      // overflow fallback: read indices from global
        for (int e = dbeg; e < dend; e++) {
            int si = (e < cnt) ? sidx[e] : src_sorted[ebeg + e];
            uint2 v = *(const uint2*)(xb + (size_t)si * FDIM + c);
            acc.x += bflo(v.x); acc.y += bfhi(v.x);
            acc.z += bflo(v.y); acc.w += bfhi(v.y);
        }
    }

    uint2 p;
    p.x = (unsigned int)f2bf(acc.x) | ((unsigned int)f2bf(acc.y) << 16);
    p.y = (unsigned int)f2bf(acc.z) | ((unsigned int)f2bf(acc.w) << 16);
    *(uint2*)(hb + (size_t)node * FDIM + c) = p;
}

// MLP over a 64-node tile, 4 nodes/thread register-blocked; fp32 math, bf16 I/O.
// Output: bf16 rows (next gather), or fused final 64->10 fp32 linear.
__global__ __launch_bounds__(256) void mlp_tile(const unsigned short* __restrict__ xb,
        const float* __restrict__ W1, const float* __restrict__ b1,
        const float* __restrict__ W2, const float* __restrict__ b2,
        const float* __restrict__ Wl, const float* __restrict__ bl,
        unsigned short* __restrict__ y, float* __restrict__ out,
        int n_nodes, int do_final) {
    __shared__ float sW1[FDIM * FDIM];
    __shared__ float sW2[FDIM * FDIM];
    __shared__ float sh[64 * HPAD];
    __shared__ float sb1[FDIM], sb2[FDIM];
    __shared__ float sWl[FDIM * 10];
    __shared__ float sbl[16];

    int tid = threadIdx.x;
    int base = blockIdx.x * 64;

    {
        const float4* W14 = (const float4*)W1;
        const float4* W24 = (const float4*)W2;
        float4* s1 = (float4*)sW1;
        float4* s2 = (float4*)sW2;
#pragma unroll
        for (int k = 0; k < 4; k++) {
            s1[tid + k * 256] = W14[tid + k * 256];
            s2[tid + k * 256] = W24[tid + k * 256];
        }
    }
    if (tid < FDIM) { sb1[tid] = b1[tid]; sb2[tid] = b2[tid]; }
    if (do_final) {
        for (int i = tid; i < FDIM * 10; i += 256) sWl[i] = Wl[i];
        if (tid < 10) sbl[tid] = bl[tid];
    }
    // stage h tile from bf16: 64 rows x 16 uint2, 4 per thread, coalesced
    {
#pragma unroll
        for (int k = 0; k < 4; k++) {
            int idx = tid + k * 256;
            int r = idx >> 4, q = (idx & 15);
            int node = base + r;
            uint2 v = make_uint2(0u, 0u);
            if (node < n_nodes) v = *(const uint2*)(xb + (size_t)node * FDIM + q * 4);
            float4 f;
            f.x = bflo(v.x); f.y = bfhi(v.x);
            f.z = bflo(v.y); f.w = bfhi(v.y);
            *(float4*)(&sh[r * HPAD + q * 4]) = f;
        }
    }
    __syncthreads();

    int ng = tid >> 4;
    int jq = (tid & 15) * 4;
    int r0 = ng * 4;

    float a[4][4];
#pragma unroll
    for (int i = 0; i < 4; i++) {
        a[i][0] = sb1[jq]; a[i][1] = sb1[jq + 1];
        a[i][2] = sb1[jq + 2]; a[i][3] = sb1[jq + 3];
    }
#pragma unroll
    for (int k0 = 0; k0 < FDIM; k0 += 4) {
        float4 w0 = *(float4*)(&sW1[(k0 + 0) * FDIM + jq]);
        float4 w1 = *(float4*)(&sW1[(k0 + 1) * FDIM + jq]);
        float4 w2 = *(float4*)(&sW1[(k0 + 2) * FDIM + jq]);
        float4 w3 = *(float4*)(&sW1[(k0 + 3) * FDIM + jq]);
#pragma unroll
        for (int i = 0; i < 4; i++) {
            float4 hv = *(float4*)(&sh[(r0 + i) * HPAD + k0]);
            a[i][0] += hv.x * w0.x + hv.y * w1.x + hv.z * w2.x + hv.w * w3.x;
            a[i][1] += hv.x * w0.y + hv.y * w1.y + hv.z * w2.y + hv.w * w3.y;
            a[i][2] += hv.x * w0.z + hv.y * w1.z + hv.z * w2.z + hv.w * w3.z;
            a[i][3] += hv.x * w0.w + hv.y * w1.w + hv.z * w2.w + hv.w * w3.w;
        }
    }
    __syncthreads();
#pragma unroll
    for (int i = 0; i < 4; i++) {
        float4 g;
        g.x = fmaxf(a[i][0], 0.f); g.y = fmaxf(a[i][1], 0.f);
        g.z = fmaxf(a[i][2], 0.f); g.w = fmaxf(a[i][3], 0.f);
        *(float4*)(&sh[(r0 + i) * HPAD + jq]) = g;
    }
    __syncthreads();

#pragma unroll
    for (int i = 0; i < 4; i++) {
        a[i][0] = sb2[jq]; a[i][1] = sb2[jq + 1];
        a[i][2] = sb2[jq + 2]; a[i][3] = sb2[jq + 3];
    }
#pragma unroll
    for (int k0 = 0; k0 < FDIM; k0 += 4) {
        float4 w0 = *(float4*)(&sW2[(k0 + 0) * FDIM + jq]);
        float4 w1 = *(float4*)(&sW2[(k0 + 1) * FDIM + jq]);
        float4 w2 = *(float4*)(&sW2[(k0 + 2) * FDIM + jq]);
        float4 w3 = *(float4*)(&sW2[(k0 + 3) * FDIM + jq]);
#pragma unroll
        for (int i = 0; i < 4; i++) {
            float4 gv = *(float4*)(&sh[(r0 + i) * HPAD + k0]);
            a[i][0] += gv.x * w0.x + gv.y * w1.x + gv.z * w2.x + gv.w * w3.x;
            a[i][1] += gv.x * w0.y + gv.y * w1.y + gv.z * w2.y + gv.w * w3.y;
            a[i][2] += gv.x * w0.z + gv.y * w1.z + gv.z * w2.z + gv.w * w3.z;
            a[i][3] += gv.x * w0.w + gv.y * w1.w + gv.z * w2.w + gv.w * w3.w;
        }
    }

    if (!do_final) {
#pragma unroll
        for (int i = 0; i < 4; i++) {
            int node = base + r0 + i;
            if (node < n_nodes) {
                float o0 = fmaxf(a[i][0], 0.f), o1 = fmaxf(a[i][1], 0.f);
                float o2 = fmaxf(a[i][2], 0.f), o3 = fmaxf(a[i][3], 0.f);
                uint2 p;
                p.x = (unsigned int)f2bf(o0) | ((unsigned int)f2bf(o1) << 16);
                p.y = (unsigned int)f2bf(o2) | ((unsigned int)f2bf(o3) << 16);
                *(uint2*)(y + (size_t)node * FDIM + jq) = p;
            }
        }
    } else {
        __syncthreads();
#pragma unroll
        for (int i = 0; i < 4; i++) {
            float4 o;
            o.x = fmaxf(a[i][0], 0.f); o.y = fmaxf(a[i][1], 0.f);
            o.z = fmaxf(a[i][2], 0.f); o.w = fmaxf(a[i][3], 0.f);
            *(float4*)(&sh[(r0 + i) * HPAD + jq]) = o;
        }
        __syncthreads();
        for (int i = tid; i < 64 * 10; i += 256) {
            int nl = i / 10, c = i % 10;
            int node = base + nl;
            if (node < n_nodes) {
                float acc = sbl[c];
#pragma unroll
                for (int k0 = 0; k0 < FDIM; k0 += 4) {
                    float4 hv = *(float4*)(&sh[nl * HPAD + k0]);
                    acc += hv.x * sWl[(k0 + 0) * 10 + c] + hv.y * sWl[(k0 + 1) * 10 + c]
                         + hv.z * sWl[(k0 + 2) * 10 + c] + hv.w * sWl[(k0 + 3) * 10 + c];
                }
                out[(size_t)node * 10 + c] = acc;
            }
        }
    }
}

extern "C" void kernel_launch(void* const* d_in, const int* in_sizes, int n_in,
                              void* d_out, int out_size, void* d_ws, size_t ws_size,
                              hipStream_t stream) {
    const float* features = (const float*)d_in[0];
    const int* edges = (const int*)d_in[1];
    int n_nodes = in_sizes[0] / FDIM;          // 50000
    int n_edges = in_sizes[1] / 2;             // 800000
    const int* src = edges;
    const int* dst = edges + n_edges;

    int nbuck = (n_nodes + BNODES - 1) / BNODES;     // 782  (<=1024)
    int nchunks = (n_edges + CHUNK - 1) / CHUNK;     // 391  (<=512)

    // workspace: ints | hb,xb0,yA,yB (bf16)
    int* hist = (int*)d_ws;
    int* chunk_off = hist + (size_t)nchunks * nbuck;
    int* bucket_total = chunk_off + (size_t)nchunks * nbuck;
    int* bucket_start = bucket_total + nbuck;
    int* row_ptr = bucket_start + nbuck + 1;
    unsigned int* packed = (unsigned int*)(row_ptr + n_nodes + 1);
    int* src_sorted = (int*)(packed + n_edges);
    size_t int_elems = 2 * (size_t)nchunks * nbuck + 2 * (size_t)nbuck + 2
                       + (size_t)n_nodes + 2 * (size_t)n_edges;
    int_elems = (int_elems + 3) & ~(size_t)3;
    size_t buf_elems = (size_t)n_nodes * FDIM;
    unsigned short* hb  = (unsigned short*)((int*)d_ws + int_elems);
    unsigned short* xb0 = hb + buf_elems;
    unsigned short* yA  = xb0 + buf_elems;
    unsigned short* yB  = yA + buf_elems;

    dim3 bs(256);
    dim3 gs_cast(((int)(buf_elems / 4) + 255) / 256);
    dim3 gs_gather((n_nodes + 15) / 16);   // 3125
    dim3 gs_tile((n_nodes + 63) / 64);     // 782

    // --- cast features to bf16 ---
    cast_bf16<<<gs_cast, bs, 0, stream>>>(features, xb0, (int)(buf_elems / 4));

    // --- build node-grouped CSR via 2-pass bucket sort ---
    bucket_hist<<<nchunks, 256, 0, stream>>>(dst, hist, n_edges, nbuck);
    scan_chunks<<<nbuck, 512, 0, stream>>>(hist, chunk_off, bucket_total, nchunks, nbuck);
    scan_buckets<<<1, 1024, 0, stream>>>(bucket_total, bucket_start, row_ptr, nbuck, n_nodes, n_edges);
    bucket_fill<<<nchunks, 256, 0, stream>>>(src, dst, bucket_start, chunk_off, packed, n_edges, nbuck);
    sort_bucket<<<nbuck, 256, 0, stream>>>(packed, bucket_start, src_sorted, row_ptr, n_nodes);

    // --- 3 GIN convs (last fuses the final linear) ---
    const float* Wl = (const float*)d_in[14];
    const float* bl = (const float*)d_in[15];
    const unsigned short* x_cur = xb0;
    unsigned short* outs[3] = {yA, yB, yA};
    for (int conv = 0; conv < 3; conv++) {
        const float* W1 = (const float*)d_in[2 + 4 * conv];
        const float* b1 = (const float*)d_in[3 + 4 * conv];
        const float* W2 = (const float*)d_in[4 + 4 * conv];
        const float* b2 = (const float*)d_in[5 + 4 * conv];
        int fin = (conv == 2) ? 1 : 0;

        gather_bf16<<<gs_gather, bs, 0, stream>>>(x_cur, row_ptr, src_sorted, hb, n_nodes);
        mlp_tile<<<gs_tile, bs, 0, stream>>>(hb, W1, b1, W2, b2, Wl, bl,
                                             outs[conv], (float*)d_out, n_nodes, fin);
        x_cur = outs[conv];
    }
}